// Round 1
// baseline (245.061 us; speedup 1.0000x reference)
//
#include <hip/hip_runtime.h>
#include <math.h>

#define BATCH 32
#define TLEN 8192
#define NCH 128          // number of chunks
#define CLEN 64          // steps per chunk
#define NROWS (BATCH*TLEN)   // 262144 rows

// ---------------------------------------------------------------------------
// HiPPO step: s <- (I - A/t) s + (x/t) * r
// (A s)[n] = (n+1)*s[n] + r[n] * sum_{m<n} r[m]*s[m]
// ---------------------------------------------------------------------------
__device__ __forceinline__ void hippo_step(float s[8], float inv_t, float xb) {
    const float R[8] = {1.0f, 1.7320508075688772f, 2.23606797749979f,
                        2.6457513110645907f, 3.0f, 3.3166247903554f,
                        3.605551275463989f, 3.872983346207417f};
    float p = 0.0f;
    #pragma unroll
    for (int n = 0; n < 8; n++) {
        float sn = s[n];
        float as = fmaf(R[n], p, (float)(n + 1) * sn);
        s[n] = fmaf(-inv_t, as, fmaf(xb, R[n], sn));
        p = fmaf(R[n], sn, p);
    }
}

// ---------------------------------------------------------------------------
// Kernel A: per-chunk transition matrix P (threads 64..71, one column each)
// and per-(b,c) chunk offset vectors V (threads 0..63), both via 64 steps.
// ---------------------------------------------------------------------------
__global__ void hippo_chunk_kernel(const float* __restrict__ x_seq,
                                   float* __restrict__ P,   // [NCH][8][8]
                                   float* __restrict__ V)   // [64][NCH][8]
{
    int chunk = blockIdx.x;
    int tid = threadIdx.x;
    if (tid >= 72) return;
    bool isP = tid >= 64;
    int col = tid - 64;
    int b = tid >> 1, c = tid & 1;

    float s[8];
    #pragma unroll
    for (int n = 0; n < 8; n++) s[n] = (isP && n == col) ? 1.0f : 0.0f;

    int t0 = chunk * CLEN;
    for (int i = 0; i < CLEN; i++) {
        float tf = (float)(t0 + i + 1);
        float inv_t = 1.0f / tf;
        float x = 0.0f;
        if (!isP) x = x_seq[((size_t)(b * TLEN + t0 + i)) * 2 + c];
        hippo_step(s, inv_t, x * inv_t);
    }
    if (isP) {
        #pragma unroll
        for (int n = 0; n < 8; n++) P[chunk * 64 + n * 8 + col] = s[n];
    } else {
        #pragma unroll
        for (int n = 0; n < 8; n++) V[(tid * NCH + chunk) * 8 + n] = s[n];
    }
}

// ---------------------------------------------------------------------------
// Kernel B: sequential composition across chunks. One thread per (b,c).
// S0[seq][chunk] = state at the start of chunk.
// ---------------------------------------------------------------------------
__global__ void hippo_compose_kernel(const float* __restrict__ P,
                                     const float* __restrict__ V,
                                     float* __restrict__ S0)
{
    int tid = threadIdx.x;   // 0..63
    float s[8];
    #pragma unroll
    for (int n = 0; n < 8; n++) s[n] = 0.0f;

    for (int chunk = 0; chunk < NCH; chunk++) {
        #pragma unroll
        for (int n = 0; n < 8; n++) S0[(tid * NCH + chunk) * 8 + n] = s[n];
        float ns[8];
        #pragma unroll
        for (int n = 0; n < 8; n++) {
            float acc = V[(tid * NCH + chunk) * 8 + n];
            #pragma unroll
            for (int m = 0; m < 8; m++)
                acc = fmaf(P[chunk * 64 + n * 8 + m], s[m], acc);
            ns[n] = acc;
        }
        #pragma unroll
        for (int n = 0; n < 8; n++) s[n] = ns[n];
    }
}

// ---------------------------------------------------------------------------
// Kernel C: replay each chunk from its start state, write transposed
// hT[16][NROWS] (plane = c*8+n) so the KAN kernel reads coalesced columns.
// ---------------------------------------------------------------------------
__global__ void hippo_expand_kernel(const float* __restrict__ x_seq,
                                    const float* __restrict__ S0,
                                    float* __restrict__ hT)
{
    int gt = blockIdx.x * blockDim.x + threadIdx.x;   // 0..8191
    int b = gt >> 8;
    int rem = gt & 255;
    int chunk = rem >> 1;
    int c = rem & 1;
    int seq = b * 2 + c;

    float s[8];
    #pragma unroll
    for (int n = 0; n < 8; n++) s[n] = S0[(seq * NCH + chunk) * 8 + n];

    int t0 = chunk * CLEN;
    for (int i = 0; i < CLEN; i++) {
        float tf = (float)(t0 + i + 1);
        float inv_t = 1.0f / tf;
        float x = x_seq[((size_t)(b * TLEN + t0 + i)) * 2 + c];
        hippo_step(s, inv_t, x * inv_t);
        size_t base = (size_t)(b * TLEN + t0 + i);
        #pragma unroll
        for (int n = 0; n < 8; n++)
            hT[(size_t)(c * 8 + n) * NROWS + base] = s[n];
    }
}

// ---------------------------------------------------------------------------
// KAN: 4-nonzero-basis closed form for uniform cubic B-spline.
// Interval m = floor((x+1.6)*5) in [0,15]; weights padded to rows of 19
// (3 zeros each side) so indices m..m+3 always hit valid LDS and
// out-of-range bases multiply zeros.
// ---------------------------------------------------------------------------
__device__ __forceinline__ void bspline4(float x, float& B0, float& B1,
                                         float& B2, float& B3, int& m)
{
    float tt = fmaf(x, 5.0f, 8.0f);        // (x + 1.6) * 5
    float fm = floorf(tt);
    float u = tt - fm;
    bool valid = (fm >= 0.0f) && (fm <= 15.0f);
    float u2 = u * u, u3 = u2 * u;
    float um = 1.0f - u;
    B0 = um * um * um * (1.0f / 6.0f);
    B3 = u3 * (1.0f / 6.0f);
    B1 = fmaf(3.0f, u3, fmaf(-6.0f, u2, 4.0f)) * (1.0f / 6.0f);
    B2 = fmaf(-3.0f, u3, fmaf(3.0f, u2, fmaf(3.0f, u, 1.0f))) * (1.0f / 6.0f);
    float msk = valid ? 1.0f : 0.0f;
    B0 *= msk; B1 *= msk; B2 *= msk; B3 *= msk;
    m = valid ? (int)fm : 0;
}

__device__ __forceinline__ float silu(float x) {
    return x / (1.0f + __expf(-x));
}

__global__ __launch_bounds__(256) void kan_kernel(
    const float* __restrict__ hT,        // [16][NROWS]
    float* __restrict__ out1T,           // [32][NROWS] scratch (planes 0..15 reused for layer-2 out)
    const float* __restrict__ wb1, const float* __restrict__ ws1,
    const float* __restrict__ wb2, const float* __restrict__ ws2,
    const float* __restrict__ wb3, const float* __restrict__ ws3,
    float* __restrict__ out)
{
    __shared__ float wlds[10032];        // phase1: ws1p[32][304]; phase2: ws2p[16][608] + ws3p[304]
    int tid = threadIdx.x;
    int row = blockIdx.x * 256 + tid;

    // ---- stage ws1 padded: wlds[o*304 + i*19 + 3 + j] = ws1[o][i*13+j]
    for (int idx = tid; idx < 9728; idx += 256) {
        int o = idx / 304;
        int k = idx - o * 304;
        int ii = k / 19;
        int jj = k - ii * 19 - 3;
        float v = 0.0f;
        if (jj >= 0 && jj < 13) v = ws1[o * 208 + ii * 13 + jj];
        wlds[idx] = v;
    }
    __syncthreads();

    // ---- layer 1: in 16 -> out 32
    float acc1[32];
    #pragma unroll
    for (int o = 0; o < 32; o++) acc1[o] = 0.0f;

    #pragma unroll 1
    for (int i = 0; i < 16; i++) {
        float x = hT[(size_t)i * NROWS + row];
        float sx = silu(x);
        float B0, B1, B2, B3; int m;
        bspline4(x, B0, B1, B2, B3, m);
        const float* wp = &wlds[i * 19 + m];
        const float* wbp = &wb1[i];
        #pragma unroll
        for (int o = 0; o < 32; o++) {
            float a = acc1[o];
            a = fmaf(sx, wbp[o * 16], a);
            const float* w = wp + o * 304;
            a = fmaf(B0, w[0], a);
            a = fmaf(B1, w[1], a);
            a = fmaf(B2, w[2], a);
            a = fmaf(B3, w[3], a);
            acc1[o] = a;
        }
    }
    #pragma unroll
    for (int o = 0; o < 32; o++) out1T[(size_t)o * NROWS + row] = acc1[o];

    __syncthreads();   // everyone done reading ws1

    // ---- stage ws2 + ws3 padded
    for (int idx = tid; idx < 10032; idx += 256) {
        float v = 0.0f;
        if (idx < 9728) {
            int o = idx / 608;
            int k = idx - o * 608;
            int ii = k / 19;
            int jj = k - ii * 19 - 3;
            if (jj >= 0 && jj < 13) v = ws2[o * 416 + ii * 13 + jj];
        } else {
            int k = idx - 9728;
            int ii = k / 19;
            int jj = k - ii * 19 - 3;
            if (jj >= 0 && jj < 13) v = ws3[ii * 13 + jj];
        }
        wlds[idx] = v;
    }
    __syncthreads();

    // ---- layer 2: in 32 -> out 16
    float acc2[16];
    #pragma unroll
    for (int o = 0; o < 16; o++) acc2[o] = 0.0f;

    #pragma unroll 1
    for (int i = 0; i < 32; i++) {
        float x = out1T[(size_t)i * NROWS + row];
        float sx = silu(x);
        float B0, B1, B2, B3; int m;
        bspline4(x, B0, B1, B2, B3, m);
        const float* wp = &wlds[i * 19 + m];
        const float* wbp = &wb2[i];
        #pragma unroll
        for (int o = 0; o < 16; o++) {
            float a = acc2[o];
            a = fmaf(sx, wbp[o * 32], a);
            const float* w = wp + o * 608;
            a = fmaf(B0, w[0], a);
            a = fmaf(B1, w[1], a);
            a = fmaf(B2, w[2], a);
            a = fmaf(B3, w[3], a);
            acc2[o] = a;
        }
    }
    // stash layer-2 output in planes 0..15 (each thread touches only its row)
    #pragma unroll
    for (int o = 0; o < 16; o++) out1T[(size_t)o * NROWS + row] = acc2[o];

    // ---- layer 3: in 16 -> out 1
    float acc3 = 0.0f;
    #pragma unroll 1
    for (int i = 0; i < 16; i++) {
        float x = out1T[(size_t)i * NROWS + row];
        float sx = silu(x);
        float B0, B1, B2, B3; int m;
        bspline4(x, B0, B1, B2, B3, m);
        const float* wp = &wlds[9728 + i * 19 + m];
        float a = acc3;
        a = fmaf(sx, wb3[i], a);
        a = fmaf(B0, wp[0], a);
        a = fmaf(B1, wp[1], a);
        a = fmaf(B2, wp[2], a);
        a = fmaf(B3, wp[3], a);
        acc3 = a;
    }
    out[row] = acc3;
}

// ---------------------------------------------------------------------------
extern "C" void kernel_launch(void* const* d_in, const int* in_sizes, int n_in,
                              void* d_out, int out_size, void* d_ws, size_t ws_size,
                              hipStream_t stream) {
    const float* x_seq = (const float*)d_in[0];
    const float* wb1   = (const float*)d_in[1];
    const float* ws1   = (const float*)d_in[2];
    const float* wb2   = (const float*)d_in[3];
    const float* ws2   = (const float*)d_in[4];
    const float* wb3   = (const float*)d_in[5];
    const float* ws3   = (const float*)d_in[6];

    float* ws    = (float*)d_ws;
    float* P     = ws;                 // 128*64          = 8192
    float* V     = ws + 8192;          // 64*128*8        = 65536
    float* S0    = ws + 73728;         // 64*128*8        = 65536
    float* hT    = ws + 139264;        // 16*262144       = 4194304
    float* out1T = ws + 4333568;       // 32*262144       = 8388608
    float* out   = (float*)d_out;

    hipLaunchKernelGGL(hippo_chunk_kernel,   dim3(NCH), dim3(128), 0, stream, x_seq, P, V);
    hipLaunchKernelGGL(hippo_compose_kernel, dim3(1),   dim3(64),  0, stream, P, V, S0);
    hipLaunchKernelGGL(hippo_expand_kernel,  dim3(32),  dim3(256), 0, stream, x_seq, S0, hT);
    hipLaunchKernelGGL(kan_kernel, dim3(NROWS / 256), dim3(256), 0, stream,
                       hT, out1T, wb1, ws1, wb2, ws2, wb3, ws3, out);
}